// Round 1
// baseline (322.336 us; speedup 1.0000x reference)
//
#include <hip/hip_runtime.h>
#include <hip/hip_bf16.h>

#define L 4096
#define DM 128
#define NH 8
#define HD 16
#define NBH 16
#define SK 41

typedef __attribute__((ext_vector_type(8))) short s16x8;
typedef __attribute__((ext_vector_type(4))) float f32x4;

__device__ __forceinline__ float bf2f(unsigned short h){ return __uint_as_float(((unsigned)h)<<16); }
__device__ __forceinline__ unsigned short f2bf(float f){
  unsigned u = __float_as_uint(f);
  u += 0x7FFFu + ((u>>16)&1u);
  return (unsigned short)(u>>16);
}

// ---------------- K1: fused QKV projection ----------------
// grid (128, 3), block 256. Each block: 64 rows x all 128 cols of one projection.
// thread: 2 rows x 16 cols (16 cols == exactly one head).
__global__ __launch_bounds__(256) void qkv_proj(
    const float* __restrict__ x,
    const float* __restrict__ Wq, const float* __restrict__ bq,
    const float* __restrict__ Wk, const float* __restrict__ bk,
    const float* __restrict__ Wv, const float* __restrict__ bv,
    unsigned short* __restrict__ Qh, unsigned short* __restrict__ Ql,
    unsigned short* __restrict__ Kh, unsigned short* __restrict__ Kl,
    float* __restrict__ Vo)
{
  const int p = blockIdx.y;
  const float* __restrict__ W    = (p==0)?Wq:((p==1)?Wk:Wv);
  const float* __restrict__ bias = (p==0)?bq:((p==1)?bk:bv);
  __shared__ float xs[64*128];
  __shared__ float ws[16*128];
  const int t = threadIdx.x;
  const long rowbase = (long)blockIdx.x*64;
  {
    const float4* xg = (const float4*)(x + rowbase*DM);
    float4* xsv = (float4*)xs;
#pragma unroll
    for (int i=0;i<8;++i) xsv[t + i*256] = xg[t + i*256];
  }
  const int cg = t & 7, rg = t >> 3;
  const int j0 = cg*16;
  float acc0[16], acc1[16];
#pragma unroll
  for (int k2=0;k2<16;++k2){ acc0[k2]=0.f; acc1[k2]=0.f; }
  for (int dc=0; dc<8; ++dc){
    __syncthreads();
    {
      const float4* wg = (const float4*)(W + dc*16*DM);
      float4* wsv = (float4*)ws;
#pragma unroll
      for (int i=0;i<2;++i) wsv[t + i*256] = wg[t + i*256];
    }
    __syncthreads();
#pragma unroll
    for (int d2=0; d2<16; ++d2){
      float w[16];
      *(float4*)(w+0)  = *(const float4*)(ws + d2*DM + j0);
      *(float4*)(w+4)  = *(const float4*)(ws + d2*DM + j0+4);
      *(float4*)(w+8)  = *(const float4*)(ws + d2*DM + j0+8);
      *(float4*)(w+12) = *(const float4*)(ws + d2*DM + j0+12);
      const float xa = xs[(rg*2)*DM + dc*16 + d2];
      const float xb = xs[(rg*2+1)*DM + dc*16 + d2];
#pragma unroll
      for (int k2=0;k2<16;++k2){
        acc0[k2] = fmaf(xa, w[k2], acc0[k2]);
        acc1[k2] = fmaf(xb, w[k2], acc1[k2]);
      }
    }
  }
  float bb[16];
  *(float4*)(bb+0) =*(const float4*)(bias+j0);
  *(float4*)(bb+4) =*(const float4*)(bias+j0+4);
  *(float4*)(bb+8) =*(const float4*)(bias+j0+8);
  *(float4*)(bb+12)=*(const float4*)(bias+j0+12);
#pragma unroll
  for (int rr=0; rr<2; ++rr){
    float* acc = rr ? acc1 : acc0;
    const long i = rowbase + rg*2 + rr;
    const int b = (int)(i>>12), li = (int)(i & 4095);
    const long o = (((long)(b*NH + cg))*L + li)*HD;
    if (p == 2){
      float ov[16];
#pragma unroll
      for (int k2=0;k2<16;++k2) ov[k2] = acc[k2] + bb[k2];
      *(float4*)(Vo+o+0)  = *(float4*)(ov+0);
      *(float4*)(Vo+o+4)  = *(float4*)(ov+4);
      *(float4*)(Vo+o+8)  = *(float4*)(ov+8);
      *(float4*)(Vo+o+12) = *(float4*)(ov+12);
    } else {
      unsigned short hv[16], lv[16];
#pragma unroll
      for (int k2=0;k2<16;++k2){
        float v = acc[k2] + bb[k2];
        unsigned short h = f2bf(v);
        hv[k2] = h;
        lv[k2] = f2bf(v - bf2f(h));
      }
      unsigned short* Hp = p ? Kh : Qh;
      unsigned short* Lp = p ? Kl : Ql;
      *(uint4*)(Hp+o)   = *(uint4*)(hv);
      *(uint4*)(Hp+o+8) = *(uint4*)(hv+8);
      *(uint4*)(Lp+o)   = *(uint4*)(lv);
      *(uint4*)(Lp+o+8) = *(uint4*)(lv+8);
    }
  }
}

// ---------------- K2: row-max of QK^T*0.25 ----------------
// grid (16 qtiles, 16 bh), block 256 (4 waves). Wave owns 4 q-subtiles (64 rows).
// Split-bf16 MFMA: A=[Qhi|Qlo]; B1=[Khi|Khi], B2=[Klo|0].
__global__ __launch_bounds__(256) void rowmax_k(
    const unsigned short* __restrict__ Qh, const unsigned short* __restrict__ Ql,
    const unsigned short* __restrict__ Kh, const unsigned short* __restrict__ Kl,
    float* __restrict__ mout)
{
  const int bh = blockIdx.y, qt = blockIdx.x;
  const int t = threadIdx.x, w = t>>6, l = t&63;
  const int half = (l>>4)&1, part = l>>5, lc = l&15;
  __shared__ __align__(16) unsigned short khs[2048];
  __shared__ __align__(16) unsigned short kls[2048];
  s16x8 aq[4];
  {
    const unsigned short* Qsrc = part ? Ql : Qh;
#pragma unroll
    for (int m=0;m<4;++m){
      const int row = qt*256 + w*64 + m*16 + lc;
      aq[m] = *(const s16x8*)(Qsrc + (((long)bh*L + row)*HD) + half*8);
    }
  }
  f32x4 rmax[4];
#pragma unroll
  for (int m=0;m<4;++m){ rmax[m][0]=rmax[m][1]=rmax[m][2]=rmax[m][3]=-3.4e38f; }
  const s16x8* khg = (const s16x8*)(Kh + (long)bh*L*HD);
  const s16x8* klg = (const s16x8*)(Kl + (long)bh*L*HD);
  s16x8 pk = khg[t], pl = klg[t];
  for (int kc=0; kc<32; ++kc){
    __syncthreads();
    ((s16x8*)khs)[t] = pk;
    ((s16x8*)kls)[t] = pl;
    if (kc+1 < 32){ pk = khg[(kc+1)*256 + t]; pl = klg[(kc+1)*256 + t]; }
    __syncthreads();
#pragma unroll
    for (int s=0;s<8;++s){
      const int key = s*16 + lc;
      s16x8 b1 = ((const s16x8*)khs)[key*2 + half];
      s16x8 b2 = {0,0,0,0,0,0,0,0};
      if (part == 0) b2 = ((const s16x8*)kls)[key*2 + half];
#pragma unroll
      for (int m=0;m<4;++m){
        f32x4 acc = {0.f,0.f,0.f,0.f};
        acc = __builtin_amdgcn_mfma_f32_16x16x32_bf16(aq[m], b2, acc, 0,0,0);
        acc = __builtin_amdgcn_mfma_f32_16x16x32_bf16(aq[m], b1, acc, 0,0,0);
#pragma unroll
        for (int r=0;r<4;++r) rmax[m][r] = fmaxf(rmax[m][r], acc[r]);
      }
    }
  }
#pragma unroll
  for (int m=0;m<4;++m){
#pragma unroll
    for (int r=0;r<4;++r){
      float v = rmax[m][r];
      v = fmaxf(v, __shfl_xor(v, 1));
      v = fmaxf(v, __shfl_xor(v, 2));
      v = fmaxf(v, __shfl_xor(v, 4));
      v = fmaxf(v, __shfl_xor(v, 8));
      rmax[m][r] = v;
    }
  }
  if (lc == 0){
    const int q4 = l>>4;
#pragma unroll
    for (int m=0;m<4;++m){
#pragma unroll
      for (int r=0;r<4;++r){
        const int row = qt*256 + w*64 + m*16 + q4*4 + r;
        mout[(long)bh*L + row] = 0.25f * rmax[m][r];
      }
    }
  }
}

// ---------------- K3: column sums of exp(s*0.25 - m[q]) ----------------
// Transposed roles: A = K (rows=keys), B = Q^T (cols=queries).
__global__ __launch_bounds__(256) void colexp_k(
    const unsigned short* __restrict__ Kh, const unsigned short* __restrict__ Kl,
    const unsigned short* __restrict__ Qh, const unsigned short* __restrict__ Ql,
    const float* __restrict__ mIn, float* __restrict__ csOut)
{
  const int bh = blockIdx.y, kt = blockIdx.x;
  const int t = threadIdx.x, w = t>>6, l = t&63;
  const int half = (l>>4)&1, part = l>>5, lc = l&15;
  __shared__ __align__(16) unsigned short qhs[2048];
  __shared__ __align__(16) unsigned short qls[2048];
  __shared__ float ms[128];
  s16x8 ak[4];
  {
    const unsigned short* Ksrc = part ? Kl : Kh;
#pragma unroll
    for (int m=0;m<4;++m){
      const int key = kt*256 + w*64 + m*16 + lc;
      ak[m] = *(const s16x8*)(Ksrc + (((long)bh*L + key)*HD) + half*8);
    }
  }
  f32x4 csum[4];
#pragma unroll
  for (int m=0;m<4;++m){ csum[m][0]=csum[m][1]=csum[m][2]=csum[m][3]=0.f; }
  const s16x8* qhg = (const s16x8*)(Qh + (long)bh*L*HD);
  const s16x8* qlg = (const s16x8*)(Ql + (long)bh*L*HD);
  const float* mg = mIn + (long)bh*L;
  s16x8 pk = qhg[t], pl = qlg[t];
  float pm = (t < 128) ? mg[t]*1.44269504f : 0.f;
  for (int qc=0; qc<32; ++qc){
    __syncthreads();
    ((s16x8*)qhs)[t] = pk;
    ((s16x8*)qls)[t] = pl;
    if (t < 128) ms[t] = pm;
    if (qc+1 < 32){
      pk = qhg[(qc+1)*256 + t]; pl = qlg[(qc+1)*256 + t];
      if (t < 128) pm = mg[(qc+1)*128 + t]*1.44269504f;
    }
    __syncthreads();
#pragma unroll
    for (int s=0;s<8;++s){
      const int qq = s*16 + lc;
      s16x8 b1 = ((const s16x8*)qhs)[qq*2 + half];
      s16x8 b2 = {0,0,0,0,0,0,0,0};
      if (part == 0) b2 = ((const s16x8*)qls)[qq*2 + half];
      const float m2 = ms[qq];
#pragma unroll
      for (int m=0;m<4;++m){
        f32x4 acc = {0.f,0.f,0.f,0.f};
        acc = __builtin_amdgcn_mfma_f32_16x16x32_bf16(ak[m], b2, acc, 0,0,0);
        acc = __builtin_amdgcn_mfma_f32_16x16x32_bf16(ak[m], b1, acc, 0,0,0);
#pragma unroll
        for (int r=0;r<4;++r)
          csum[m][r] += exp2f(fmaf(acc[r], 0.36067376022224085f, -m2));
      }
    }
  }
#pragma unroll
  for (int m=0;m<4;++m){
#pragma unroll
    for (int r=0;r<4;++r){
      float v = csum[m][r];
      v += __shfl_xor(v, 1);
      v += __shfl_xor(v, 2);
      v += __shfl_xor(v, 4);
      v += __shfl_xor(v, 8);
      csum[m][r] = v;
    }
  }
  if (lc == 0){
    const int k4 = l>>4;
#pragma unroll
    for (int m=0;m<4;++m){
#pragma unroll
      for (int r=0;r<4;++r){
        const int key = kt*256 + w*64 + m*16 + k4*4 + r;
        csOut[(long)bh*L + key] = csum[m][r];
      }
    }
  }
}

// ---------------- K4: top-41 + gather Ks/Vs ----------------
// One wave per (b,h). Iterative global argmax, 41 rounds.
__global__ __launch_bounds__(64) void topk_gather(
    const float* __restrict__ cs,
    const unsigned short* __restrict__ Kh, const unsigned short* __restrict__ Kl,
    const float* __restrict__ V,
    float* __restrict__ Ks, float* __restrict__ Vs)
{
  const int bh = blockIdx.x;
  const int l = threadIdx.x;
  __shared__ int sidx[SK];
  float v[64];
#pragma unroll
  for (int j=0;j<64;++j) v[j] = cs[(long)bh*L + j*64 + l];
  for (int it=0; it<SK; ++it){
    float bestv = -3.4e38f; int bestj = 0;
#pragma unroll
    for (int j=0;j<64;++j){
      if (v[j] > bestv){ bestv = v[j]; bestj = j; }
    }
    int bidx = bestj*64 + l;
#pragma unroll
    for (int off=1; off<64; off<<=1){
      float ov = __shfl_xor(bestv, off);
      int oi = __shfl_xor(bidx, off);
      if (ov > bestv || (ov == bestv && oi < bidx)){ bestv = ov; bidx = oi; }
    }
    if (l == (bidx & 63)){
      const int wj = bidx >> 6;
#pragma unroll
      for (int j=0;j<64;++j) if (j == wj) v[j] = -3.4e38f;
    }
    if (l == 0) sidx[it] = bidx;
  }
  __syncthreads();
  for (int i=l; i<SK*HD; i+=64){
    const int j = i>>4, dd = i&15;
    const int key = sidx[j];
    const long src = ((long)bh*L + key)*HD + dd;
    Ks[(long)bh*SK*HD + i] = bf2f(Kh[src]) + bf2f(Kl[src]);
    Vs[(long)bh*SK*HD + i] = V[src];
  }
}

// ---------------- K5: sampled attention (online softmax over 41 keys) ----------------
__global__ __launch_bounds__(256) void sattn(
    const unsigned short* __restrict__ Qh, const unsigned short* __restrict__ Ql,
    const float* __restrict__ Ks, const float* __restrict__ Vs,
    float* __restrict__ AO)
{
  const int bh = blockIdx.y, qb = blockIdx.x;
  const int t = threadIdx.x;
  __shared__ float ks[SK*HD], vs[SK*HD];
  for (int i=t; i<SK*HD; i+=256){
    ks[i] = Ks[(long)bh*SK*HD + i];
    vs[i] = Vs[(long)bh*SK*HD + i];
  }
  __syncthreads();
  const int q = qb*256 + t;
  const long qo = ((long)bh*L + q)*HD;
  float qv[16];
  {
    s16x8 h0 = *(const s16x8*)(Qh+qo);
    s16x8 h1 = *(const s16x8*)(Qh+qo+8);
    s16x8 l0 = *(const s16x8*)(Ql+qo);
    s16x8 l1 = *(const s16x8*)(Ql+qo+8);
#pragma unroll
    for (int d=0; d<8; ++d){
      qv[d]   = bf2f((unsigned short)h0[d]) + bf2f((unsigned short)l0[d]);
      qv[d+8] = bf2f((unsigned short)h1[d]) + bf2f((unsigned short)l1[d]);
    }
  }
  float mrun = -3.4e38f, lrun = 0.f, out[16];
#pragma unroll
  for (int d=0; d<16; ++d) out[d] = 0.f;
  for (int j=0; j<SK; ++j){
    float s = 0.f;
#pragma unroll
    for (int d=0; d<16; ++d) s = fmaf(qv[d], ks[j*HD+d], s);
    s *= 0.25f;
    if (s > mrun){
      const float c = __expf(mrun - s);
      lrun *= c;
#pragma unroll
      for (int d=0; d<16; ++d) out[d] *= c;
      mrun = s;
    }
    const float p = __expf(s - mrun);
    lrun += p;
#pragma unroll
    for (int d=0; d<16; ++d) out[d] = fmaf(p, vs[j*HD+d], out[d]);
  }
  const float inv = 1.f / lrun;
  const int b = bh>>3, h = bh&7;
  float* op = AO + ((long)b*L + q)*DM + h*HD;
  float ov[16];
#pragma unroll
  for (int d=0; d<16; ++d) ov[d] = out[d]*inv;
  *(float4*)(op+0)  = *(float4*)(ov+0);
  *(float4*)(op+4)  = *(float4*)(ov+4);
  *(float4*)(op+8)  = *(float4*)(ov+8);
  *(float4*)(op+12) = *(float4*)(ov+12);
}

// ---------------- K6: output projection ----------------
__global__ __launch_bounds__(256) void out_proj(
    const float* __restrict__ A, const float* __restrict__ Wo,
    const float* __restrict__ bo, float* __restrict__ out)
{
  __shared__ float xs[64*128];
  __shared__ float ws[16*128];
  const int t = threadIdx.x;
  const long rowbase = (long)blockIdx.x*64;
  {
    const float4* xg = (const float4*)(A + rowbase*DM);
    float4* xsv = (float4*)xs;
#pragma unroll
    for (int i=0;i<8;++i) xsv[t + i*256] = xg[t + i*256];
  }
  const int cg = t & 7, rg = t >> 3;
  const int j0 = cg*16;
  float acc0[16], acc1[16];
#pragma unroll
  for (int k2=0;k2<16;++k2){ acc0[k2]=0.f; acc1[k2]=0.f; }
  for (int dc=0; dc<8; ++dc){
    __syncthreads();
    {
      const float4* wg = (const float4*)(Wo + dc*16*DM);
      float4* wsv = (float4*)ws;
#pragma unroll
      for (int i=0;i<2;++i) wsv[t + i*256] = wg[t + i*256];
    }
    __syncthreads();
#pragma unroll
    for (int d2=0; d2<16; ++d2){
      float w[16];
      *(float4*)(w+0)  = *(const float4*)(ws + d2*DM + j0);
      *(float4*)(w+4)  = *(const float4*)(ws + d2*DM + j0+4);
      *(float4*)(w+8)  = *(const float4*)(ws + d2*DM + j0+8);
      *(float4*)(w+12) = *(const float4*)(ws + d2*DM + j0+12);
      const float xa = xs[(rg*2)*DM + dc*16 + d2];
      const float xb = xs[(rg*2+1)*DM + dc*16 + d2];
#pragma unroll
      for (int k2=0;k2<16;++k2){
        acc0[k2] = fmaf(xa, w[k2], acc0[k2]);
        acc1[k2] = fmaf(xb, w[k2], acc1[k2]);
      }
    }
  }
  float bb[16];
  *(float4*)(bb+0) =*(const float4*)(bo+j0);
  *(float4*)(bb+4) =*(const float4*)(bo+j0+4);
  *(float4*)(bb+8) =*(const float4*)(bo+j0+8);
  *(float4*)(bb+12)=*(const float4*)(bo+j0+12);
#pragma unroll
  for (int rr=0; rr<2; ++rr){
    float* acc = rr ? acc1 : acc0;
    const long i = rowbase + rg*2 + rr;
    float ov[16];
#pragma unroll
    for (int k2=0;k2<16;++k2) ov[k2] = acc[k2] + bb[k2];
    float* op = out + i*DM + j0;
    *(float4*)(op+0)  = *(float4*)(ov+0);
    *(float4*)(op+4)  = *(float4*)(ov+4);
    *(float4*)(op+8)  = *(float4*)(ov+8);
    *(float4*)(op+12) = *(float4*)(ov+12);
  }
}

extern "C" void kernel_launch(void* const* d_in, const int* in_sizes, int n_in,
                              void* d_out, int out_size, void* d_ws, size_t ws_size,
                              hipStream_t stream)
{
  const float* x  = (const float*)d_in[0];
  const float* Wq = (const float*)d_in[1];
  const float* bq = (const float*)d_in[2];
  const float* Wk = (const float*)d_in[3];
  const float* bk = (const float*)d_in[4];
  const float* Wv = (const float*)d_in[5];
  const float* bv = (const float*)d_in[6];
  const float* Wo = (const float*)d_in[7];
  const float* bo = (const float*)d_in[8];
  float* out = (float*)d_out;

  char* wsp = (char*)d_ws;
  size_t o = 0;
  auto alloc = [&](size_t bytes)->char*{
    char* p = wsp + o; o += (bytes + 255) & ~(size_t)255; return p;
  };
  unsigned short* Qh = (unsigned short*)alloc((size_t)NBH*L*HD*2);
  unsigned short* Ql = (unsigned short*)alloc((size_t)NBH*L*HD*2);
  unsigned short* Kh = (unsigned short*)alloc((size_t)NBH*L*HD*2);
  unsigned short* Kl = (unsigned short*)alloc((size_t)NBH*L*HD*2);
  float* Vv   = (float*)alloc((size_t)NBH*L*HD*4);
  float* mrow = (float*)alloc((size_t)NBH*L*4);
  float* csum = (float*)alloc((size_t)NBH*L*4);
  float* Ks   = (float*)alloc((size_t)NBH*SK*HD*4);
  float* Vs   = (float*)alloc((size_t)NBH*SK*HD*4);
  float* AO   = (float*)alloc((size_t)2*L*DM*4);

  qkv_proj<<<dim3(128,3),256,0,stream>>>(x,Wq,bq,Wk,bk,Wv,bv,Qh,Ql,Kh,Kl,Vv);
  rowmax_k<<<dim3(16,16),256,0,stream>>>(Qh,Ql,Kh,Kl,mrow);
  colexp_k<<<dim3(16,16),256,0,stream>>>(Kh,Kl,Qh,Ql,mrow,csum);
  topk_gather<<<16,64,0,stream>>>(csum,Kh,Kl,Vv,Ks,Vs);
  sattn<<<dim3(16,16),256,0,stream>>>(Qh,Ql,Ks,Vs,AO);
  out_proj<<<128,256,0,stream>>>(AO,Wo,bo,out);
}

// Round 2
// 290.242 us; speedup vs baseline: 1.1106x; 1.1106x over previous
//
#include <hip/hip_runtime.h>
#include <hip/hip_bf16.h>

#define L 4096
#define DM 128
#define NH 8
#define HD 16
#define NBH 16
#define SK 41
#define NSPLIT 4

typedef __attribute__((ext_vector_type(8))) short s16x8;
typedef __attribute__((ext_vector_type(4))) float f32x4;

__device__ __forceinline__ float bf2f(unsigned short h){ return __uint_as_float(((unsigned)h)<<16); }
__device__ __forceinline__ unsigned short f2bf(float f){
  unsigned u = __float_as_uint(f);
  u += 0x7FFFu + ((u>>16)&1u);
  return (unsigned short)(u>>16);
}
__device__ __forceinline__ float fast_exp2(float x){
  float r;
  asm("v_exp_f32 %0, %1" : "=v"(r) : "v"(x));
  return r;
}

// ---------------- K1: fused QKV projection ----------------
__global__ __launch_bounds__(256) void qkv_proj(
    const float* __restrict__ x,
    const float* __restrict__ Wq, const float* __restrict__ bq,
    const float* __restrict__ Wk, const float* __restrict__ bk,
    const float* __restrict__ Wv, const float* __restrict__ bv,
    unsigned short* __restrict__ Qh, unsigned short* __restrict__ Ql,
    unsigned short* __restrict__ Kh, unsigned short* __restrict__ Kl,
    float* __restrict__ Vo)
{
  const int p = blockIdx.y;
  const float* __restrict__ W    = (p==0)?Wq:((p==1)?Wk:Wv);
  const float* __restrict__ bias = (p==0)?bq:((p==1)?bk:bv);
  __shared__ float xs[64*128];
  __shared__ float ws[16*128];
  const int t = threadIdx.x;
  const long rowbase = (long)blockIdx.x*64;
  {
    const float4* xg = (const float4*)(x + rowbase*DM);
    float4* xsv = (float4*)xs;
#pragma unroll
    for (int i=0;i<8;++i) xsv[t + i*256] = xg[t + i*256];
  }
  const int cg = t & 7, rg = t >> 3;
  const int j0 = cg*16;
  float acc0[16], acc1[16];
#pragma unroll
  for (int k2=0;k2<16;++k2){ acc0[k2]=0.f; acc1[k2]=0.f; }
  for (int dc=0; dc<8; ++dc){
    __syncthreads();
    {
      const float4* wg = (const float4*)(W + dc*16*DM);
      float4* wsv = (float4*)ws;
#pragma unroll
      for (int i=0;i<2;++i) wsv[t + i*256] = wg[t + i*256];
    }
    __syncthreads();
#pragma unroll
    for (int d2=0; d2<16; ++d2){
      float w[16];
      *(float4*)(w+0)  = *(const float4*)(ws + d2*DM + j0);
      *(float4*)(w+4)  = *(const float4*)(ws + d2*DM + j0+4);
      *(float4*)(w+8)  = *(const float4*)(ws + d2*DM + j0+8);
      *(float4*)(w+12) = *(const float4*)(ws + d2*DM + j0+12);
      const float xa = xs[(rg*2)*DM + dc*16 + d2];
      const float xb = xs[(rg*2+1)*DM + dc*16 + d2];
#pragma unroll
      for (int k2=0;k2<16;++k2){
        acc0[k2] = fmaf(xa, w[k2], acc0[k2]);
        acc1[k2] = fmaf(xb, w[k2], acc1[k2]);
      }
    }
  }
  float bb[16];
  *(float4*)(bb+0) =*(const float4*)(bias+j0);
  *(float4*)(bb+4) =*(const float4*)(bias+j0+4);
  *(float4*)(bb+8) =*(const float4*)(bias+j0+8);
  *(float4*)(bb+12)=*(const float4*)(bias+j0+12);
#pragma unroll
  for (int rr=0; rr<2; ++rr){
    float* acc = rr ? acc1 : acc0;
    const long i = rowbase + rg*2 + rr;
    const int b = (int)(i>>12), li = (int)(i & 4095);
    const long o = (((long)(b*NH + cg))*L + li)*HD;
    if (p == 2){
      float ov[16];
#pragma unroll
      for (int k2=0;k2<16;++k2) ov[k2] = acc[k2] + bb[k2];
      *(float4*)(Vo+o+0)  = *(float4*)(ov+0);
      *(float4*)(Vo+o+4)  = *(float4*)(ov+4);
      *(float4*)(Vo+o+8)  = *(float4*)(ov+8);
      *(float4*)(Vo+o+12) = *(float4*)(ov+12);
    } else {
      unsigned short hv[16], lv[16];
#pragma unroll
      for (int k2=0;k2<16;++k2){
        float v = acc[k2] + bb[k2];
        unsigned short h = f2bf(v);
        hv[k2] = h;
        lv[k2] = f2bf(v - bf2f(h));
      }
      unsigned short* Hp = p ? Kh : Qh;
      unsigned short* Lp = p ? Kl : Ql;
      *(uint4*)(Hp+o)   = *(uint4*)(hv);
      *(uint4*)(Hp+o+8) = *(uint4*)(hv+8);
      *(uint4*)(Lp+o)   = *(uint4*)(lv);
      *(uint4*)(Lp+o+8) = *(uint4*)(lv+8);
    }
  }
}

// ---------------- K2: partial row-max of QK^T*0.25 ----------------
// grid (16 qtiles, 16 bh, 4 kslice), block 256 (4 waves).
__global__ __launch_bounds__(256) void rowmax_k(
    const unsigned short* __restrict__ Qh, const unsigned short* __restrict__ Ql,
    const unsigned short* __restrict__ Kh, const unsigned short* __restrict__ Kl,
    float* __restrict__ mpart)
{
  const int bh = blockIdx.y, qt = blockIdx.x, ks = blockIdx.z;
  const int t = threadIdx.x, w = t>>6, l = t&63;
  const int half = (l>>4)&1, part = l>>5, lc = l&15;
  __shared__ __align__(16) unsigned short khs[2048];
  __shared__ __align__(16) unsigned short kls[2048];
  s16x8 aq[4];
  {
    const unsigned short* Qsrc = part ? Ql : Qh;
#pragma unroll
    for (int m=0;m<4;++m){
      const int row = qt*256 + w*64 + m*16 + lc;
      aq[m] = *(const s16x8*)(Qsrc + (((long)bh*L + row)*HD) + half*8);
    }
  }
  f32x4 rmax[4];
#pragma unroll
  for (int m=0;m<4;++m){ rmax[m][0]=rmax[m][1]=rmax[m][2]=rmax[m][3]=-3.4e38f; }
  const s16x8* khg = (const s16x8*)(Kh + (long)bh*L*HD);
  const s16x8* klg = (const s16x8*)(Kl + (long)bh*L*HD);
  const int c0 = ks*8;
  s16x8 pk = khg[c0*256 + t], pl = klg[c0*256 + t];
  for (int kc=0; kc<8; ++kc){
    __syncthreads();
    ((s16x8*)khs)[t] = pk;
    ((s16x8*)kls)[t] = pl;
    if (kc+1 < 8){ pk = khg[(c0+kc+1)*256 + t]; pl = klg[(c0+kc+1)*256 + t]; }
    __syncthreads();
#pragma unroll
    for (int s=0;s<8;++s){
      const int key = s*16 + lc;
      s16x8 b1 = ((const s16x8*)khs)[key*2 + half];
      s16x8 b2 = {0,0,0,0,0,0,0,0};
      if (part == 0) b2 = ((const s16x8*)kls)[key*2 + half];
#pragma unroll
      for (int m=0;m<4;++m){
        f32x4 acc = {0.f,0.f,0.f,0.f};
        acc = __builtin_amdgcn_mfma_f32_16x16x32_bf16(aq[m], b2, acc, 0,0,0);
        acc = __builtin_amdgcn_mfma_f32_16x16x32_bf16(aq[m], b1, acc, 0,0,0);
#pragma unroll
        for (int r=0;r<4;++r) rmax[m][r] = fmaxf(rmax[m][r], acc[r]);
      }
    }
  }
#pragma unroll
  for (int m=0;m<4;++m){
#pragma unroll
    for (int r=0;r<4;++r){
      float v = rmax[m][r];
      v = fmaxf(v, __shfl_xor(v, 1));
      v = fmaxf(v, __shfl_xor(v, 2));
      v = fmaxf(v, __shfl_xor(v, 4));
      v = fmaxf(v, __shfl_xor(v, 8));
      rmax[m][r] = v;
    }
  }
  if (lc == 0){
    const int q4 = l>>4;
#pragma unroll
    for (int m=0;m<4;++m){
#pragma unroll
      for (int r=0;r<4;++r){
        const int row = qt*256 + w*64 + m*16 + q4*4 + r;
        mpart[((long)(ks*NBH + bh))*L + row] = 0.25f * rmax[m][r];
      }
    }
  }
}

// ---------------- K3: partial column sums of exp(s*0.25 - m[q]) ----------------
// grid (16 ktiles, 16 bh, 4 qslice), block 256 (4 waves).
__global__ __launch_bounds__(256) void colexp_k(
    const unsigned short* __restrict__ Kh, const unsigned short* __restrict__ Kl,
    const unsigned short* __restrict__ Qh, const unsigned short* __restrict__ Ql,
    const float* __restrict__ mpart, float* __restrict__ cspart)
{
  const int bh = blockIdx.y, kt = blockIdx.x, qs = blockIdx.z;
  const int t = threadIdx.x, w = t>>6, l = t&63;
  const int half = (l>>4)&1, part = l>>5, lc = l&15;
  __shared__ __align__(16) unsigned short qhs[2048];
  __shared__ __align__(16) unsigned short qls[2048];
  __shared__ float ms[128];
  s16x8 ak[4];
  {
    const unsigned short* Ksrc = part ? Kl : Kh;
#pragma unroll
    for (int m=0;m<4;++m){
      const int key = kt*256 + w*64 + m*16 + lc;
      ak[m] = *(const s16x8*)(Ksrc + (((long)bh*L + key)*HD) + half*8);
    }
  }
  f32x4 csum[4];
#pragma unroll
  for (int m=0;m<4;++m){ csum[m][0]=csum[m][1]=csum[m][2]=csum[m][3]=0.f; }
  const s16x8* qhg = (const s16x8*)(Qh + (long)bh*L*HD);
  const s16x8* qlg = (const s16x8*)(Ql + (long)bh*L*HD);
  const float* mg0 = mpart + (long)(0*NBH + bh)*L;
  const float* mg1 = mpart + (long)(1*NBH + bh)*L;
  const float* mg2 = mpart + (long)(2*NBH + bh)*L;
  const float* mg3 = mpart + (long)(3*NBH + bh)*L;
  const int c0 = qs*8;
  s16x8 pk = qhg[c0*256 + t], pl = qlg[c0*256 + t];
  float pm = 0.f;
  if (t < 128){
    const long qi = (long)c0*128 + t;
    pm = fmaxf(fmaxf(mg0[qi], mg1[qi]), fmaxf(mg2[qi], mg3[qi])) * 1.44269504f;
  }
  for (int qc=0; qc<8; ++qc){
    __syncthreads();
    ((s16x8*)qhs)[t] = pk;
    ((s16x8*)qls)[t] = pl;
    if (t < 128) ms[t] = pm;
    if (qc+1 < 8){
      pk = qhg[(c0+qc+1)*256 + t]; pl = qlg[(c0+qc+1)*256 + t];
      if (t < 128){
        const long qi = (long)(c0+qc+1)*128 + t;
        pm = fmaxf(fmaxf(mg0[qi], mg1[qi]), fmaxf(mg2[qi], mg3[qi])) * 1.44269504f;
      }
    }
    __syncthreads();
#pragma unroll
    for (int s=0;s<8;++s){
      const int qq = s*16 + lc;
      s16x8 b1 = ((const s16x8*)qhs)[qq*2 + half];
      s16x8 b2 = {0,0,0,0,0,0,0,0};
      if (part == 0) b2 = ((const s16x8*)qls)[qq*2 + half];
      const float m2 = ms[qq];
#pragma unroll
      for (int m=0;m<4;++m){
        f32x4 acc = {0.f,0.f,0.f,0.f};
        acc = __builtin_amdgcn_mfma_f32_16x16x32_bf16(ak[m], b2, acc, 0,0,0);
        acc = __builtin_amdgcn_mfma_f32_16x16x32_bf16(ak[m], b1, acc, 0,0,0);
#pragma unroll
        for (int r=0;r<4;++r)
          csum[m][r] += fast_exp2(fmaf(acc[r], 0.36067376022224085f, -m2));
      }
    }
  }
#pragma unroll
  for (int m=0;m<4;++m){
#pragma unroll
    for (int r=0;r<4;++r){
      float v = csum[m][r];
      v += __shfl_xor(v, 1);
      v += __shfl_xor(v, 2);
      v += __shfl_xor(v, 4);
      v += __shfl_xor(v, 8);
      csum[m][r] = v;
    }
  }
  if (lc == 0){
    const int k4 = l>>4;
#pragma unroll
    for (int m=0;m<4;++m){
#pragma unroll
      for (int r=0;r<4;++r){
        const int key = kt*256 + w*64 + m*16 + k4*4 + r;
        cspart[((long)(qs*NBH + bh))*L + key] = csum[m][r];
      }
    }
  }
}

// ---------------- K4: top-41 + gather Ks/Vs ----------------
__global__ __launch_bounds__(64) void topk_gather(
    const float* __restrict__ cspart,
    const unsigned short* __restrict__ Kh, const unsigned short* __restrict__ Kl,
    const float* __restrict__ V,
    float* __restrict__ Ks, float* __restrict__ Vs)
{
  const int bh = blockIdx.x;
  const int l = threadIdx.x;
  __shared__ int sidx[SK];
  float v[64];
#pragma unroll
  for (int j=0;j<64;++j){
    const long idx = j*64 + l;
    float s = 0.f;
#pragma unroll
    for (int p=0;p<NSPLIT;++p) s += cspart[((long)(p*NBH + bh))*L + idx];
    v[j] = s;
  }
  for (int it=0; it<SK; ++it){
    float bestv = -3.4e38f; int bestj = 0;
#pragma unroll
    for (int j=0;j<64;++j){
      if (v[j] > bestv){ bestv = v[j]; bestj = j; }
    }
    int bidx = bestj*64 + l;
#pragma unroll
    for (int off=1; off<64; off<<=1){
      float ov = __shfl_xor(bestv, off);
      int oi = __shfl_xor(bidx, off);
      if (ov > bestv || (ov == bestv && oi < bidx)){ bestv = ov; bidx = oi; }
    }
    if (l == (bidx & 63)){
      const int wj = bidx >> 6;
#pragma unroll
      for (int j=0;j<64;++j) if (j == wj) v[j] = -3.4e38f;
    }
    if (l == 0) sidx[it] = bidx;
  }
  __syncthreads();
  for (int i=l; i<SK*HD; i+=64){
    const int j = i>>4, dd = i&15;
    const int key = sidx[j];
    const long src = ((long)bh*L + key)*HD + dd;
    Ks[(long)bh*SK*HD + i] = bf2f(Kh[src]) + bf2f(Kl[src]);
    Vs[(long)bh*SK*HD + i] = V[src];
  }
}

// ---------------- K5: sampled attention (online softmax over 41 keys) ----------------
__global__ __launch_bounds__(256) void sattn(
    const unsigned short* __restrict__ Qh, const unsigned short* __restrict__ Ql,
    const float* __restrict__ Ks, const float* __restrict__ Vs,
    float* __restrict__ AO)
{
  const int bh = blockIdx.y, qb = blockIdx.x;
  const int t = threadIdx.x;
  __shared__ float ks[SK*HD], vs[SK*HD];
  for (int i=t; i<SK*HD; i+=256){
    ks[i] = Ks[(long)bh*SK*HD + i];
    vs[i] = Vs[(long)bh*SK*HD + i];
  }
  __syncthreads();
  const int q = qb*256 + t;
  const long qo = ((long)bh*L + q)*HD;
  float qv[16];
  {
    s16x8 h0 = *(const s16x8*)(Qh+qo);
    s16x8 h1 = *(const s16x8*)(Qh+qo+8);
    s16x8 l0 = *(const s16x8*)(Ql+qo);
    s16x8 l1 = *(const s16x8*)(Ql+qo+8);
#pragma unroll
    for (int d=0; d<8; ++d){
      qv[d]   = bf2f((unsigned short)h0[d]) + bf2f((unsigned short)l0[d]);
      qv[d+8] = bf2f((unsigned short)h1[d]) + bf2f((unsigned short)l1[d]);
    }
  }
  float mrun = -3.4e38f, lrun = 0.f, out[16];
#pragma unroll
  for (int d=0; d<16; ++d) out[d] = 0.f;
  for (int j=0; j<SK; ++j){
    float s = 0.f;
#pragma unroll
    for (int d=0; d<16; ++d) s = fmaf(qv[d], ks[j*HD+d], s);
    s *= 0.25f;
    if (s > mrun){
      const float c = __expf(mrun - s);
      lrun *= c;
#pragma unroll
      for (int d=0; d<16; ++d) out[d] *= c;
      mrun = s;
    }
    const float p = __expf(s - mrun);
    lrun += p;
#pragma unroll
    for (int d=0; d<16; ++d) out[d] = fmaf(p, vs[j*HD+d], out[d]);
  }
  const float inv = 1.f / lrun;
  const int b = bh>>3, h = bh&7;
  float* op = AO + ((long)b*L + q)*DM + h*HD;
  float ov[16];
#pragma unroll
  for (int d=0; d<16; ++d) ov[d] = out[d]*inv;
  *(float4*)(op+0)  = *(float4*)(ov+0);
  *(float4*)(op+4)  = *(float4*)(ov+4);
  *(float4*)(op+8)  = *(float4*)(ov+8);
  *(float4*)(op+12) = *(float4*)(ov+12);
}

// ---------------- K6: output projection ----------------
__global__ __launch_bounds__(256) void out_proj(
    const float* __restrict__ A, const float* __restrict__ Wo,
    const float* __restrict__ bo, float* __restrict__ out)
{
  __shared__ float xs[64*128];
  __shared__ float ws[16*128];
  const int t = threadIdx.x;
  const long rowbase = (long)blockIdx.x*64;
  {
    const float4* xg = (const float4*)(A + rowbase*DM);
    float4* xsv = (float4*)xs;
#pragma unroll
    for (int i=0;i<8;++i) xsv[t + i*256] = xg[t + i*256];
  }
  const int cg = t & 7, rg = t >> 3;
  const int j0 = cg*16;
  float acc0[16], acc1[16];
#pragma unroll
  for (int k2=0;k2<16;++k2){ acc0[k2]=0.f; acc1[k2]=0.f; }
  for (int dc=0; dc<8; ++dc){
    __syncthreads();
    {
      const float4* wg = (const float4*)(Wo + dc*16*DM);
      float4* wsv = (float4*)ws;
#pragma unroll
      for (int i=0;i<2;++i) wsv[t + i*256] = wg[t + i*256];
    }
    __syncthreads();
#pragma unroll
    for (int d2=0; d2<16; ++d2){
      float w[16];
      *(float4*)(w+0)  = *(const float4*)(ws + d2*DM + j0);
      *(float4*)(w+4)  = *(const float4*)(ws + d2*DM + j0+4);
      *(float4*)(w+8)  = *(const float4*)(ws + d2*DM + j0+8);
      *(float4*)(w+12) = *(const float4*)(ws + d2*DM + j0+12);
      const float xa = xs[(rg*2)*DM + dc*16 + d2];
      const float xb = xs[(rg*2+1)*DM + dc*16 + d2];
#pragma unroll
      for (int k2=0;k2<16;++k2){
        acc0[k2] = fmaf(xa, w[k2], acc0[k2]);
        acc1[k2] = fmaf(xb, w[k2], acc1[k2]);
      }
    }
  }
  float bb[16];
  *(float4*)(bb+0) =*(const float4*)(bo+j0);
  *(float4*)(bb+4) =*(const float4*)(bo+j0+4);
  *(float4*)(bb+8) =*(const float4*)(bo+j0+8);
  *(float4*)(bb+12)=*(const float4*)(bo+j0+12);
#pragma unroll
  for (int rr=0; rr<2; ++rr){
    float* acc = rr ? acc1 : acc0;
    const long i = rowbase + rg*2 + rr;
    float ov[16];
#pragma unroll
    for (int k2=0;k2<16;++k2) ov[k2] = acc[k2] + bb[k2];
    float* op = out + i*DM + j0;
    *(float4*)(op+0)  = *(float4*)(ov+0);
    *(float4*)(op+4)  = *(float4*)(ov+4);
    *(float4*)(op+8)  = *(float4*)(ov+8);
    *(float4*)(op+12) = *(float4*)(ov+12);
  }
}

extern "C" void kernel_launch(void* const* d_in, const int* in_sizes, int n_in,
                              void* d_out, int out_size, void* d_ws, size_t ws_size,
                              hipStream_t stream)
{
  const float* x  = (const float*)d_in[0];
  const float* Wq = (const float*)d_in[1];
  const float* bq = (const float*)d_in[2];
  const float* Wk = (const float*)d_in[3];
  const float* bk = (const float*)d_in[4];
  const float* Wv = (const float*)d_in[5];
  const float* bv = (const float*)d_in[6];
  const float* Wo = (const float*)d_in[7];
  const float* bo = (const float*)d_in[8];
  float* out = (float*)d_out;

  char* wsp = (char*)d_ws;
  size_t o = 0;
  auto alloc = [&](size_t bytes)->char*{
    char* p = wsp + o; o += (bytes + 255) & ~(size_t)255; return p;
  };
  unsigned short* Qh = (unsigned short*)alloc((size_t)NBH*L*HD*2);
  unsigned short* Ql = (unsigned short*)alloc((size_t)NBH*L*HD*2);
  unsigned short* Kh = (unsigned short*)alloc((size_t)NBH*L*HD*2);
  unsigned short* Kl = (unsigned short*)alloc((size_t)NBH*L*HD*2);
  float* Vv    = (float*)alloc((size_t)NBH*L*HD*4);
  float* mpart = (float*)alloc((size_t)NSPLIT*NBH*L*4);
  float* cspart= (float*)alloc((size_t)NSPLIT*NBH*L*4);
  float* Ks    = (float*)alloc((size_t)NBH*SK*HD*4);
  float* Vs    = (float*)alloc((size_t)NBH*SK*HD*4);
  float* AO    = (float*)alloc((size_t)2*L*DM*4);

  qkv_proj<<<dim3(128,3),256,0,stream>>>(x,Wq,bq,Wk,bk,Wv,bv,Qh,Ql,Kh,Kl,Vv);
  rowmax_k<<<dim3(16,16,NSPLIT),256,0,stream>>>(Qh,Ql,Kh,Kl,mpart);
  colexp_k<<<dim3(16,16,NSPLIT),256,0,stream>>>(Kh,Kl,Qh,Ql,mpart,cspart);
  topk_gather<<<16,64,0,stream>>>(cspart,Kh,Kl,Vv,Ks,Vs);
  sattn<<<dim3(16,16),256,0,stream>>>(Qh,Ql,Ks,Vs,AO);
  out_proj<<<128,256,0,stream>>>(AO,Wo,bo,out);
}

// Round 3
// 260.474 us; speedup vs baseline: 1.2375x; 1.1143x over previous
//
#include <hip/hip_runtime.h>
#include <hip/hip_bf16.h>

#define L 4096
#define DM 128
#define NH 8
#define HD 16
#define NBH 16
#define SK 41
#define NSPLIT 4

typedef __attribute__((ext_vector_type(8))) short s16x8;
typedef __attribute__((ext_vector_type(4))) float f32x4;

__device__ __forceinline__ float bf2f(unsigned short h){ return __uint_as_float(((unsigned)h)<<16); }
__device__ __forceinline__ unsigned short f2bf(float f){
  unsigned u = __float_as_uint(f);
  u += 0x7FFFu + ((u>>16)&1u);
  return (unsigned short)(u>>16);
}
__device__ __forceinline__ float fast_exp2(float x){
  float r;
  asm("v_exp_f32 %0, %1" : "=v"(r) : "v"(x));
  return r;
}

// ---------------- K1: fused QKV projection ----------------
__global__ __launch_bounds__(256) void qkv_proj(
    const float* __restrict__ x,
    const float* __restrict__ Wq, const float* __restrict__ bq,
    const float* __restrict__ Wk, const float* __restrict__ bk,
    const float* __restrict__ Wv, const float* __restrict__ bv,
    unsigned short* __restrict__ Qh, unsigned short* __restrict__ Ql,
    unsigned short* __restrict__ Kh, unsigned short* __restrict__ Kl,
    float* __restrict__ Vo)
{
  const int p = blockIdx.y;
  const float* __restrict__ W    = (p==0)?Wq:((p==1)?Wk:Wv);
  const float* __restrict__ bias = (p==0)?bq:((p==1)?bk:bv);
  __shared__ float xs[64*128];
  __shared__ float ws[16*128];
  const int t = threadIdx.x;
  const long rowbase = (long)blockIdx.x*64;
  {
    const float4* xg = (const float4*)(x + rowbase*DM);
    float4* xsv = (float4*)xs;
#pragma unroll
    for (int i=0;i<8;++i) xsv[t + i*256] = xg[t + i*256];
  }
  const int cg = t & 7, rg = t >> 3;
  const int j0 = cg*16;
  float acc0[16], acc1[16];
#pragma unroll
  for (int k2=0;k2<16;++k2){ acc0[k2]=0.f; acc1[k2]=0.f; }
  for (int dc=0; dc<8; ++dc){
    __syncthreads();
    {
      const float4* wg = (const float4*)(W + dc*16*DM);
      float4* wsv = (float4*)ws;
#pragma unroll
      for (int i=0;i<2;++i) wsv[t + i*256] = wg[t + i*256];
    }
    __syncthreads();
#pragma unroll
    for (int d2=0; d2<16; ++d2){
      float w[16];
      *(float4*)(w+0)  = *(const float4*)(ws + d2*DM + j0);
      *(float4*)(w+4)  = *(const float4*)(ws + d2*DM + j0+4);
      *(float4*)(w+8)  = *(const float4*)(ws + d2*DM + j0+8);
      *(float4*)(w+12) = *(const float4*)(ws + d2*DM + j0+12);
      const float xa = xs[(rg*2)*DM + dc*16 + d2];
      const float xb = xs[(rg*2+1)*DM + dc*16 + d2];
#pragma unroll
      for (int k2=0;k2<16;++k2){
        acc0[k2] = fmaf(xa, w[k2], acc0[k2]);
        acc1[k2] = fmaf(xb, w[k2], acc1[k2]);
      }
    }
  }
  float bb[16];
  *(float4*)(bb+0) =*(const float4*)(bias+j0);
  *(float4*)(bb+4) =*(const float4*)(bias+j0+4);
  *(float4*)(bb+8) =*(const float4*)(bias+j0+8);
  *(float4*)(bb+12)=*(const float4*)(bias+j0+12);
#pragma unroll
  for (int rr=0; rr<2; ++rr){
    float* acc = rr ? acc1 : acc0;
    const long i = rowbase + rg*2 + rr;
    const int b = (int)(i>>12), li = (int)(i & 4095);
    const long o = (((long)(b*NH + cg))*L + li)*HD;
    if (p == 2){
      float ov[16];
#pragma unroll
      for (int k2=0;k2<16;++k2) ov[k2] = acc[k2] + bb[k2];
      *(float4*)(Vo+o+0)  = *(float4*)(ov+0);
      *(float4*)(Vo+o+4)  = *(float4*)(ov+4);
      *(float4*)(Vo+o+8)  = *(float4*)(ov+8);
      *(float4*)(Vo+o+12) = *(float4*)(ov+12);
    } else {
      unsigned short hv[16], lv[16];
#pragma unroll
      for (int k2=0;k2<16;++k2){
        float v = acc[k2] + bb[k2];
        unsigned short h = f2bf(v);
        hv[k2] = h;
        lv[k2] = f2bf(v - bf2f(h));
      }
      unsigned short* Hp = p ? Kh : Qh;
      unsigned short* Lp = p ? Kl : Ql;
      *(uint4*)(Hp+o)   = *(uint4*)(hv);
      *(uint4*)(Hp+o+8) = *(uint4*)(hv+8);
      *(uint4*)(Lp+o)   = *(uint4*)(lv);
      *(uint4*)(Lp+o+8) = *(uint4*)(lv+8);
    }
  }
}

// ---------------- K2: partial row-max of QK^T*0.25 ----------------
__global__ __launch_bounds__(256) void rowmax_k(
    const unsigned short* __restrict__ Qh, const unsigned short* __restrict__ Ql,
    const unsigned short* __restrict__ Kh, const unsigned short* __restrict__ Kl,
    float* __restrict__ mpart)
{
  const int bh = blockIdx.y, qt = blockIdx.x, ks = blockIdx.z;
  const int t = threadIdx.x, w = t>>6, l = t&63;
  const int half = (l>>4)&1, part = l>>5, lc = l&15;
  __shared__ __align__(16) unsigned short khs[2048];
  __shared__ __align__(16) unsigned short kls[2048];
  s16x8 aq[4];
  {
    const unsigned short* Qsrc = part ? Ql : Qh;
#pragma unroll
    for (int m=0;m<4;++m){
      const int row = qt*256 + w*64 + m*16 + lc;
      aq[m] = *(const s16x8*)(Qsrc + (((long)bh*L + row)*HD) + half*8);
    }
  }
  f32x4 rmax[4];
#pragma unroll
  for (int m=0;m<4;++m){ rmax[m][0]=rmax[m][1]=rmax[m][2]=rmax[m][3]=-3.4e38f; }
  const s16x8* khg = (const s16x8*)(Kh + (long)bh*L*HD);
  const s16x8* klg = (const s16x8*)(Kl + (long)bh*L*HD);
  const int c0 = ks*8;
  s16x8 pk = khg[c0*256 + t], pl = klg[c0*256 + t];
  for (int kc=0; kc<8; ++kc){
    __syncthreads();
    ((s16x8*)khs)[t] = pk;
    ((s16x8*)kls)[t] = pl;
    if (kc+1 < 8){ pk = khg[(c0+kc+1)*256 + t]; pl = klg[(c0+kc+1)*256 + t]; }
    __syncthreads();
#pragma unroll
    for (int s=0;s<8;++s){
      const int key = s*16 + lc;
      s16x8 b1 = ((const s16x8*)khs)[key*2 + half];
      s16x8 b2 = {0,0,0,0,0,0,0,0};
      if (part == 0) b2 = ((const s16x8*)kls)[key*2 + half];
#pragma unroll
      for (int m=0;m<4;++m){
        f32x4 acc = {0.f,0.f,0.f,0.f};
        acc = __builtin_amdgcn_mfma_f32_16x16x32_bf16(aq[m], b2, acc, 0,0,0);
        acc = __builtin_amdgcn_mfma_f32_16x16x32_bf16(aq[m], b1, acc, 0,0,0);
#pragma unroll
        for (int r=0;r<4;++r) rmax[m][r] = fmaxf(rmax[m][r], acc[r]);
      }
    }
  }
#pragma unroll
  for (int m=0;m<4;++m){
#pragma unroll
    for (int r=0;r<4;++r){
      float v = rmax[m][r];
      v = fmaxf(v, __shfl_xor(v, 1));
      v = fmaxf(v, __shfl_xor(v, 2));
      v = fmaxf(v, __shfl_xor(v, 4));
      v = fmaxf(v, __shfl_xor(v, 8));
      rmax[m][r] = v;
    }
  }
  if (lc == 0){
    const int q4 = l>>4;
#pragma unroll
    for (int m=0;m<4;++m){
#pragma unroll
      for (int r=0;r<4;++r){
        const int row = qt*256 + w*64 + m*16 + q4*4 + r;
        mpart[((long)(ks*NBH + bh))*L + row] = 0.25f * rmax[m][r];
      }
    }
  }
}

// ---------------- K3: partial column sums of exp(s*0.25 - m[q]) ----------------
__global__ __launch_bounds__(256) void colexp_k(
    const unsigned short* __restrict__ Kh, const unsigned short* __restrict__ Kl,
    const unsigned short* __restrict__ Qh, const unsigned short* __restrict__ Ql,
    const float* __restrict__ mpart, float* __restrict__ cspart)
{
  const int bh = blockIdx.y, kt = blockIdx.x, qs = blockIdx.z;
  const int t = threadIdx.x, w = t>>6, l = t&63;
  const int half = (l>>4)&1, part = l>>5, lc = l&15;
  __shared__ __align__(16) unsigned short qhs[2048];
  __shared__ __align__(16) unsigned short qls[2048];
  __shared__ float ms[128];
  s16x8 ak[4];
  {
    const unsigned short* Ksrc = part ? Kl : Kh;
#pragma unroll
    for (int m=0;m<4;++m){
      const int key = kt*256 + w*64 + m*16 + lc;
      ak[m] = *(const s16x8*)(Ksrc + (((long)bh*L + key)*HD) + half*8);
    }
  }
  f32x4 csum[4];
#pragma unroll
  for (int m=0;m<4;++m){ csum[m][0]=csum[m][1]=csum[m][2]=csum[m][3]=0.f; }
  const s16x8* qhg = (const s16x8*)(Qh + (long)bh*L*HD);
  const s16x8* qlg = (const s16x8*)(Ql + (long)bh*L*HD);
  const float* mg0 = mpart + (long)(0*NBH + bh)*L;
  const float* mg1 = mpart + (long)(1*NBH + bh)*L;
  const float* mg2 = mpart + (long)(2*NBH + bh)*L;
  const float* mg3 = mpart + (long)(3*NBH + bh)*L;
  const int c0 = qs*8;
  s16x8 pk = qhg[c0*256 + t], pl = qlg[c0*256 + t];
  float pm = 0.f;
  if (t < 128){
    const long qi = (long)c0*128 + t;
    pm = fmaxf(fmaxf(mg0[qi], mg1[qi]), fmaxf(mg2[qi], mg3[qi])) * 1.44269504f;
  }
  for (int qc=0; qc<8; ++qc){
    __syncthreads();
    ((s16x8*)qhs)[t] = pk;
    ((s16x8*)qls)[t] = pl;
    if (t < 128) ms[t] = pm;
    if (qc+1 < 8){
      pk = qhg[(c0+qc+1)*256 + t]; pl = qlg[(c0+qc+1)*256 + t];
      if (t < 128){
        const long qi = (long)(c0+qc+1)*128 + t;
        pm = fmaxf(fmaxf(mg0[qi], mg1[qi]), fmaxf(mg2[qi], mg3[qi])) * 1.44269504f;
      }
    }
    __syncthreads();
#pragma unroll
    for (int s=0;s<8;++s){
      const int qq = s*16 + lc;
      s16x8 b1 = ((const s16x8*)qhs)[qq*2 + half];
      s16x8 b2 = {0,0,0,0,0,0,0,0};
      if (part == 0) b2 = ((const s16x8*)qls)[qq*2 + half];
      const float m2 = ms[qq];
#pragma unroll
      for (int m=0;m<4;++m){
        f32x4 acc = {0.f,0.f,0.f,0.f};
        acc = __builtin_amdgcn_mfma_f32_16x16x32_bf16(ak[m], b2, acc, 0,0,0);
        acc = __builtin_amdgcn_mfma_f32_16x16x32_bf16(ak[m], b1, acc, 0,0,0);
#pragma unroll
        for (int r=0;r<4;++r)
          csum[m][r] += fast_exp2(fmaf(acc[r], 0.36067376022224085f, -m2));
      }
    }
  }
#pragma unroll
  for (int m=0;m<4;++m){
#pragma unroll
    for (int r=0;r<4;++r){
      float v = csum[m][r];
      v += __shfl_xor(v, 1);
      v += __shfl_xor(v, 2);
      v += __shfl_xor(v, 4);
      v += __shfl_xor(v, 8);
      csum[m][r] = v;
    }
  }
  if (lc == 0){
    const int k4 = l>>4;
#pragma unroll
    for (int m=0;m<4;++m){
#pragma unroll
      for (int r=0;r<4;++r){
        const int key = kt*256 + w*64 + m*16 + k4*4 + r;
        cspart[((long)(qs*NBH + bh))*L + key] = csum[m][r];
      }
    }
  }
}

// ---------------- K4: radix-select top-41 + gather Ks/Vs ----------------
// One 256-thread block per (b,h). Positive floats: uint bits are order-preserving.
__global__ __launch_bounds__(256) void topk_gather(
    const float* __restrict__ cspart,
    const unsigned short* __restrict__ Kh, const unsigned short* __restrict__ Kl,
    const float* __restrict__ V,
    float* __restrict__ Ks, float* __restrict__ Vs)
{
  const int bh = blockIdx.x;
  const int t = threadIdx.x;
  __shared__ float vals[4096];
  __shared__ unsigned hist[2048];
  __shared__ unsigned suf[256];
  __shared__ int meta[4];          // 0:B 1:c_above 2:nsel 3:ncand
  __shared__ int sel[SK];
  __shared__ int sorted[SK];
  __shared__ int candi[4096];
  __shared__ float candv[4096];
  __shared__ float wbv[4]; __shared__ int wbi[4]; __shared__ int wbp[4];

  for (int i=t;i<2048;i+=256) hist[i]=0u;
  if (t==0){ meta[2]=0; meta[3]=0; }
  __syncthreads();
  // load + combine partial column sums, histogram top-11 bits
  for (int i=t;i<4096;i+=256){
    float s=0.f;
#pragma unroll
    for (int p=0;p<NSPLIT;++p) s += cspart[((long)(p*NBH+bh))*L + i];
    vals[i]=s;
    atomicAdd(&hist[__float_as_uint(s)>>21], 1u);
  }
  __syncthreads();
  // chunk sums (8 buckets/thread) + suffix scan over 256 chunks
  {
    unsigned c=0;
#pragma unroll
    for (int b=0;b<8;++b) c += hist[t*8+b];
    suf[t]=c;
  }
  __syncthreads();
  for (int off=1; off<256; off<<=1){
    unsigned add = (t+off<256)? suf[t+off] : 0u;
    __syncthreads();
    suf[t] += add;
    __syncthreads();
  }
  // find threshold bucket B
  {
    unsigned mysuf = suf[t];
    unsigned nxt = (t==255)?0u:suf[t+1];
    if (mysuf >= SK && nxt < SK){
      unsigned running = nxt;
      for (int b=t*8+7; b>=t*8; --b){
        unsigned h=hist[b];
        if (running + h >= SK){ meta[0]=b; meta[1]=(int)running; break; }
        running += h;
      }
    }
  }
  __syncthreads();
  const int B = meta[0];
  // collect: buckets>B selected outright; bucket==B are candidates
  for (int i=t;i<4096;i+=256){
    int b = (int)(__float_as_uint(vals[i])>>21);
    if (b > B){
      int p = atomicAdd(&meta[2],1);
      sel[p]=i;
    } else if (b == B){
      int p = atomicAdd(&meta[3],1);
      candi[p]=i; candv[p]=vals[i];
    }
  }
  __syncthreads();
  const int nsel = meta[2];
  const int nc   = meta[3];
  const int r    = SK - nsel;
  // block-parallel iterative argmax for remaining r picks
  for (int it=0; it<r; ++it){
    float bv=-1.f; int bi=0x7fffffff, bp=-1;
    for (int j=t;j<nc;j+=256){
      float v=candv[j];
      if (v>bv || (v==bv && candi[j]<bi)){ bv=v; bi=candi[j]; bp=j; }
    }
#pragma unroll
    for (int off=1;off<64;off<<=1){
      float ov=__shfl_xor(bv,off); int oi=__shfl_xor(bi,off); int op=__shfl_xor(bp,off);
      if (ov>bv || (ov==bv && oi<bi)){ bv=ov; bi=oi; bp=op; }
    }
    if ((t&63)==0){ int w=t>>6; wbv[w]=bv; wbi[w]=bi; wbp[w]=bp; }
    __syncthreads();
    if (t==0){
      float fv=wbv[0]; int fi=wbi[0], fp=wbp[0];
      for (int w=1;w<4;++w){
        if (wbv[w]>fv || (wbv[w]==fv && wbi[w]<fi)){ fv=wbv[w]; fi=wbi[w]; fp=wbp[w]; }
      }
      sel[nsel+it]=fi; candv[fp]=-1.f;
    }
    __syncthreads();
  }
  // rank-sort the 41 indices for deterministic order
  if (t<SK){
    int x=sel[t]; int rk=0;
    for (int j=0;j<SK;++j) rk += (sel[j]<x);
    sorted[rk]=x;
  }
  __syncthreads();
  // gather
  for (int i=t;i<SK*HD;i+=256){
    const int j=i>>4, dd=i&15;
    const int key=sorted[j];
    const long src=((long)bh*L+key)*HD+dd;
    Ks[(long)bh*SK*HD+i]=bf2f(Kh[src])+bf2f(Kl[src]);
    Vs[(long)bh*SK*HD+i]=V[src];
  }
}

// ---------------- K5: sampled attention (online softmax over 41 keys) ----------------
__global__ __launch_bounds__(256) void sattn(
    const unsigned short* __restrict__ Qh, const unsigned short* __restrict__ Ql,
    const float* __restrict__ Ks, const float* __restrict__ Vs,
    float* __restrict__ AO)
{
  const int bh = blockIdx.y, qb = blockIdx.x;
  const int t = threadIdx.x;
  __shared__ float ks[SK*HD], vs[SK*HD];
  for (int i=t; i<SK*HD; i+=256){
    ks[i] = Ks[(long)bh*SK*HD + i];
    vs[i] = Vs[(long)bh*SK*HD + i];
  }
  __syncthreads();
  const int q = qb*256 + t;
  const long qo = ((long)bh*L + q)*HD;
  float qv[16];
  {
    s16x8 h0 = *(const s16x8*)(Qh+qo);
    s16x8 h1 = *(const s16x8*)(Qh+qo+8);
    s16x8 l0 = *(const s16x8*)(Ql+qo);
    s16x8 l1 = *(const s16x8*)(Ql+qo+8);
#pragma unroll
    for (int d=0; d<8; ++d){
      qv[d]   = bf2f((unsigned short)h0[d]) + bf2f((unsigned short)l0[d]);
      qv[d+8] = bf2f((unsigned short)h1[d]) + bf2f((unsigned short)l1[d]);
    }
  }
  float mrun = -3.4e38f, lrun = 0.f, out[16];
#pragma unroll
  for (int d=0; d<16; ++d) out[d] = 0.f;
  for (int j=0; j<SK; ++j){
    float s = 0.f;
#pragma unroll
    for (int d=0; d<16; ++d) s = fmaf(qv[d], ks[j*HD+d], s);
    s *= 0.25f;
    if (s > mrun){
      const float c = __expf(mrun - s);
      lrun *= c;
#pragma unroll
      for (int d=0; d<16; ++d) out[d] *= c;
      mrun = s;
    }
    const float p = __expf(s - mrun);
    lrun += p;
#pragma unroll
    for (int d=0; d<16; ++d) out[d] = fmaf(p, vs[j*HD+d], out[d]);
  }
  const float inv = 1.f / lrun;
  const int b = bh>>3, h = bh&7;
  float* op = AO + ((long)b*L + q)*DM + h*HD;
  float ov[16];
#pragma unroll
  for (int d=0; d<16; ++d) ov[d] = out[d]*inv;
  *(float4*)(op+0)  = *(float4*)(ov+0);
  *(float4*)(op+4)  = *(float4*)(ov+4);
  *(float4*)(op+8)  = *(float4*)(ov+8);
  *(float4*)(op+12) = *(float4*)(ov+12);
}

// ---------------- K6: output projection ----------------
__global__ __launch_bounds__(256) void out_proj(
    const float* __restrict__ A, const float* __restrict__ Wo,
    const float* __restrict__ bo, float* __restrict__ out)
{
  __shared__ float xs[64*128];
  __shared__ float ws[16*128];
  const int t = threadIdx.x;
  const long rowbase = (long)blockIdx.x*64;
  {
    const float4* xg = (const float4*)(A + rowbase*DM);
    float4* xsv = (float4*)xs;
#pragma unroll
    for (int i=0;i<8;++i) xsv[t + i*256] = xg[t + i*256];
  }
  const int cg = t & 7, rg = t >> 3;
  const int j0 = cg*16;
  float acc0[16], acc1[16];
#pragma unroll
  for (int k2=0;k2<16;++k2){ acc0[k2]=0.f; acc1[k2]=0.f; }
  for (int dc=0; dc<8; ++dc){
    __syncthreads();
    {
      const float4* wg = (const float4*)(Wo + dc*16*DM);
      float4* wsv = (float4*)ws;
#pragma unroll
      for (int i=0;i<2;++i) wsv[t + i*256] = wg[t + i*256];
    }
    __syncthreads();
#pragma unroll
    for (int d2=0; d2<16; ++d2){
      float w[16];
      *(float4*)(w+0)  = *(const float4*)(ws + d2*DM + j0);
      *(float4*)(w+4)  = *(const float4*)(ws + d2*DM + j0+4);
      *(float4*)(w+8)  = *(const float4*)(ws + d2*DM + j0+8);
      *(float4*)(w+12) = *(const float4*)(ws + d2*DM + j0+12);
      const float xa = xs[(rg*2)*DM + dc*16 + d2];
      const float xb = xs[(rg*2+1)*DM + dc*16 + d2];
#pragma unroll
      for (int k2=0;k2<16;++k2){
        acc0[k2] = fmaf(xa, w[k2], acc0[k2]);
        acc1[k2] = fmaf(xb, w[k2], acc1[k2]);
      }
    }
  }
  float bb[16];
  *(float4*)(bb+0) =*(const float4*)(bo+j0);
  *(float4*)(bb+4) =*(const float4*)(bo+j0+4);
  *(float4*)(bb+8) =*(const float4*)(bo+j0+8);
  *(float4*)(bb+12)=*(const float4*)(bo+j0+12);
#pragma unroll
  for (int rr=0; rr<2; ++rr){
    float* acc = rr ? acc1 : acc0;
    const long i = rowbase + rg*2 + rr;
    float ov[16];
#pragma unroll
    for (int k2=0;k2<16;++k2) ov[k2] = acc[k2] + bb[k2];
    float* op = out + i*DM + j0;
    *(float4*)(op+0)  = *(float4*)(ov+0);
    *(float4*)(op+4)  = *(float4*)(ov+4);
    *(float4*)(op+8)  = *(float4*)(ov+8);
    *(float4*)(op+12) = *(float4*)(ov+12);
  }
}

extern "C" void kernel_launch(void* const* d_in, const int* in_sizes, int n_in,
                              void* d_out, int out_size, void* d_ws, size_t ws_size,
                              hipStream_t stream)
{
  const float* x  = (const float*)d_in[0];
  const float* Wq = (const float*)d_in[1];
  const float* bq = (const float*)d_in[2];
  const float* Wk = (const float*)d_in[3];
  const float* bk = (const float*)d_in[4];
  const float* Wv = (const float*)d_in[5];
  const float* bv = (const float*)d_in[6];
  const float* Wo = (const float*)d_in[7];
  const float* bo = (const float*)d_in[8];
  float* out = (float*)d_out;

  char* wsp = (char*)d_ws;
  size_t o = 0;
  auto alloc = [&](size_t bytes)->char*{
    char* p = wsp + o; o += (bytes + 255) & ~(size_t)255; return p;
  };
  unsigned short* Qh = (unsigned short*)alloc((size_t)NBH*L*HD*2);
  unsigned short* Ql = (unsigned short*)alloc((size_t)NBH*L*HD*2);
  unsigned short* Kh = (unsigned short*)alloc((size_t)NBH*L*HD*2);
  unsigned short* Kl = (unsigned short*)alloc((size_t)NBH*L*HD*2);
  float* Vv    = (float*)alloc((size_t)NBH*L*HD*4);
  float* mpart = (float*)alloc((size_t)NSPLIT*NBH*L*4);
  float* cspart= (float*)alloc((size_t)NSPLIT*NBH*L*4);
  float* Ks    = (float*)alloc((size_t)NBH*SK*HD*4);
  float* Vs    = (float*)alloc((size_t)NBH*SK*HD*4);
  float* AO    = (float*)alloc((size_t)2*L*DM*4);

  qkv_proj<<<dim3(128,3),256,0,stream>>>(x,Wq,bq,Wk,bk,Wv,bv,Qh,Ql,Kh,Kl,Vv);
  rowmax_k<<<dim3(16,16,NSPLIT),256,0,stream>>>(Qh,Ql,Kh,Kl,mpart);
  colexp_k<<<dim3(16,16,NSPLIT),256,0,stream>>>(Kh,Kl,Qh,Ql,mpart,cspart);
  topk_gather<<<16,256,0,stream>>>(cspart,Kh,Kl,Vv,Ks,Vs);
  sattn<<<dim3(16,16),256,0,stream>>>(Qh,Ql,Ks,Vs,AO);
  out_proj<<<128,256,0,stream>>>(AO,Wo,bo,out);
}

// Round 4
// 200.460 us; speedup vs baseline: 1.6080x; 1.2994x over previous
//
#include <hip/hip_runtime.h>
#include <hip/hip_bf16.h>

#define L 4096
#define DM 128
#define NH 8
#define HD 16
#define NBH 16
#define SK 41
#define NSPLIT 8
#define KCH (32/NSPLIT)

typedef __attribute__((ext_vector_type(8))) short s16x8;
typedef __attribute__((ext_vector_type(4))) float f32x4;

__device__ __forceinline__ float bf2f(unsigned short h){ return __uint_as_float(((unsigned)h)<<16); }
__device__ __forceinline__ unsigned short f2bf(float f){
  unsigned u = __float_as_uint(f);
  u += 0x7FFFu + ((u>>16)&1u);
  return (unsigned short)(u>>16);
}
__device__ __forceinline__ float fast_exp2(float x){
  float r;
  asm("v_exp_f32 %0, %1" : "=v"(r) : "v"(x));
  return r;
}

// ---------------- K0: prep — split x to bf16 hi/lo; pack W's into MFMA frag layout ----------------
// Wpack layout (per proj p): elem [((kc*2+gp)*128 + n)*8 + j] = W[(kc*16+gp*8+j)*128 + n]
__global__ __launch_bounds__(256) void prep(
    const float* __restrict__ x,
    const float* __restrict__ Wq, const float* __restrict__ Wk,
    const float* __restrict__ Wv, const float* __restrict__ Wo,
    unsigned short* __restrict__ Xh, unsigned short* __restrict__ Xl,
    unsigned short* __restrict__ Wph, unsigned short* __restrict__ Wpl)
{
  const int t = threadIdx.x;
  const int blk = blockIdx.x;
  if (blk < 1024){
    const long base = (long)blk*1024 + t*4;
    float4 v = *(const float4*)(x + base);
    unsigned short h[4], lo[4];
    h[0]=f2bf(v.x); lo[0]=f2bf(v.x - bf2f(h[0]));
    h[1]=f2bf(v.y); lo[1]=f2bf(v.y - bf2f(h[1]));
    h[2]=f2bf(v.z); lo[2]=f2bf(v.z - bf2f(h[2]));
    h[3]=f2bf(v.w); lo[3]=f2bf(v.w - bf2f(h[3]));
    *(uint2*)(Xh+base) = *(uint2*)h;
    *(uint2*)(Xl+base) = *(uint2*)lo;
  } else {
    const int e = (blk-1024)*256 + t;   // 0..65535
    const int p = e >> 14;
    const int idx = e & 16383;
    const int j = idx & 7;
    const int f = idx >> 3;
    const int n = f & 127;
    const int kcg = f >> 7;             // 0..15
    const int k = (kcg>>1)*16 + (kcg&1)*8 + j;
    const float* W = (p==0)?Wq:((p==1)?Wk:((p==2)?Wv:Wo));
    const float v = W[k*128 + n];
    const unsigned short h = f2bf(v);
    Wph[e] = h;
    Wpl[e] = f2bf(v - bf2f(h));
  }
}

// ---------------- K1: MFMA QKV projection ----------------
// grid (32, 3), block 256 (4 waves). Wave: 64 rows x 128 cols, K=128.
// Exact split: mfma(A=[xh|xl], [wh|wh]) + mfma(A, [wl|wl]) = (xh+xl)(wh+wl).
__global__ __launch_bounds__(256) void proj_mfma(
    const unsigned short* __restrict__ Xh, const unsigned short* __restrict__ Xl,
    const unsigned short* __restrict__ Wph, const unsigned short* __restrict__ Wpl,
    const float* __restrict__ bq, const float* __restrict__ bk, const float* __restrict__ bv,
    unsigned short* __restrict__ Qh, unsigned short* __restrict__ Ql,
    unsigned short* __restrict__ Kh, unsigned short* __restrict__ Kl,
    float* __restrict__ Vo)
{
  const int p = blockIdx.y;
  const float* __restrict__ bias = (p==0)?bq:((p==1)?bk:bv);
  __shared__ __align__(16) unsigned short wh[16384];
  __shared__ __align__(16) unsigned short wl[16384];
  const int t = threadIdx.x;
  {
    const uint4* gh = (const uint4*)(Wph + (long)p*16384);
    const uint4* gl = (const uint4*)(Wpl + (long)p*16384);
    uint4* sh = (uint4*)wh; uint4* sl = (uint4*)wl;
#pragma unroll
    for (int i=0;i<8;++i){ sh[t + i*256] = gh[t + i*256]; sl[t + i*256] = gl[t + i*256]; }
  }
  __syncthreads();
  const int w = t>>6, l = t&63;
  const int lc = l&15, g = l>>4;
  const int mbase = blockIdx.x*256 + w*64;
  f32x4 acc[4][8];
#pragma unroll
  for (int mt=0;mt<4;++mt)
#pragma unroll
    for (int nt=0;nt<8;++nt){ acc[mt][nt][0]=0.f; acc[mt][nt][1]=0.f; acc[mt][nt][2]=0.f; acc[mt][nt][3]=0.f; }
  const unsigned short* __restrict__ Asrc = (g<2)? Xh : Xl;
  const int koff = (g&1)*8;
  for (int kc=0; kc<8; ++kc){
    s16x8 a[4];
#pragma unroll
    for (int mt=0;mt<4;++mt)
      a[mt] = *(const s16x8*)(Asrc + ((long)(mbase + mt*16 + lc))*128 + kc*16 + koff);
#pragma unroll
    for (int nt=0;nt<8;++nt){
      const int fi = (kc*2+(g&1))*128 + nt*16 + lc;
      s16x8 b1 = ((const s16x8*)wh)[fi];
      s16x8 b2 = ((const s16x8*)wl)[fi];
#pragma unroll
      for (int mt=0;mt<4;++mt){
        acc[mt][nt] = __builtin_amdgcn_mfma_f32_16x16x32_bf16(a[mt], b1, acc[mt][nt], 0,0,0);
        acc[mt][nt] = __builtin_amdgcn_mfma_f32_16x16x32_bf16(a[mt], b2, acc[mt][nt], 0,0,0);
      }
    }
  }
#pragma unroll
  for (int nt=0;nt<8;++nt){
    const float bb = bias[nt*16 + lc];
#pragma unroll
    for (int mt=0;mt<4;++mt){
#pragma unroll
      for (int r=0;r<4;++r){
        const int row = mbase + mt*16 + g*4 + r;
        const float v = acc[mt][nt][r] + bb;
        const int b = row>>12, li = row&4095;
        const long o = (((long)(b*NH + nt))*L + li)*HD + lc;
        if (p==2){
          Vo[o] = v;
        } else {
          const unsigned short h = f2bf(v);
          const unsigned short lo2 = f2bf(v - bf2f(h));
          if (p==0){ Qh[o]=h; Ql[o]=lo2; } else { Kh[o]=h; Kl[o]=lo2; }
        }
      }
    }
  }
}

// ---------------- K2: partial row-max of QK^T*0.25 ----------------
__global__ __launch_bounds__(256) void rowmax_k(
    const unsigned short* __restrict__ Qh, const unsigned short* __restrict__ Ql,
    const unsigned short* __restrict__ Kh, const unsigned short* __restrict__ Kl,
    float* __restrict__ mpart)
{
  const int bh = blockIdx.y, qt = blockIdx.x, ks = blockIdx.z;
  const int t = threadIdx.x, w = t>>6, l = t&63;
  const int half = (l>>4)&1, part = l>>5, lc = l&15;
  __shared__ __align__(16) unsigned short khs[2048];
  __shared__ __align__(16) unsigned short kls[2048];
  s16x8 aq[4];
  {
    const unsigned short* Qsrc = part ? Ql : Qh;
#pragma unroll
    for (int m=0;m<4;++m){
      const int row = qt*256 + w*64 + m*16 + lc;
      aq[m] = *(const s16x8*)(Qsrc + (((long)bh*L + row)*HD) + half*8);
    }
  }
  f32x4 rmax[4];
#pragma unroll
  for (int m=0;m<4;++m){ rmax[m][0]=rmax[m][1]=rmax[m][2]=rmax[m][3]=-3.4e38f; }
  const s16x8* khg = (const s16x8*)(Kh + (long)bh*L*HD);
  const s16x8* klg = (const s16x8*)(Kl + (long)bh*L*HD);
  const int c0 = ks*KCH;
  s16x8 pk = khg[c0*256 + t], pl = klg[c0*256 + t];
  for (int kc=0; kc<KCH; ++kc){
    __syncthreads();
    ((s16x8*)khs)[t] = pk;
    ((s16x8*)kls)[t] = pl;
    if (kc+1 < KCH){ pk = khg[(c0+kc+1)*256 + t]; pl = klg[(c0+kc+1)*256 + t]; }
    __syncthreads();
#pragma unroll
    for (int s=0;s<8;++s){
      const int key = s*16 + lc;
      s16x8 b1 = ((const s16x8*)khs)[key*2 + half];
      s16x8 b2 = ((const s16x8*)kls)[key*2 + half];
#pragma unroll
      for (int m=0;m<4;++m){
        f32x4 acc = {0.f,0.f,0.f,0.f};
        acc = __builtin_amdgcn_mfma_f32_16x16x32_bf16(aq[m], b2, acc, 0,0,0);
        acc = __builtin_amdgcn_mfma_f32_16x16x32_bf16(aq[m], b1, acc, 0,0,0);
#pragma unroll
        for (int r=0;r<4;++r) rmax[m][r] = fmaxf(rmax[m][r], acc[r]);
      }
    }
  }
#pragma unroll
  for (int m=0;m<4;++m){
#pragma unroll
    for (int r=0;r<4;++r){
      float v = rmax[m][r];
      v = fmaxf(v, __shfl_xor(v, 1));
      v = fmaxf(v, __shfl_xor(v, 2));
      v = fmaxf(v, __shfl_xor(v, 4));
      v = fmaxf(v, __shfl_xor(v, 8));
      rmax[m][r] = v;
    }
  }
  if (lc == 0){
    const int q4 = l>>4;
#pragma unroll
    for (int m=0;m<4;++m){
#pragma unroll
      for (int r=0;r<4;++r){
        const int row = qt*256 + w*64 + m*16 + q4*4 + r;
        mpart[((long)(ks*NBH + bh))*L + row] = 0.25f * rmax[m][r];
      }
    }
  }
}

// ---------------- K3: partial column sums of exp(s*0.25 - m[q]) ----------------
__global__ __launch_bounds__(256) void colexp_k(
    const unsigned short* __restrict__ Kh, const unsigned short* __restrict__ Kl,
    const unsigned short* __restrict__ Qh, const unsigned short* __restrict__ Ql,
    const float* __restrict__ mpart, float* __restrict__ cspart)
{
  const int bh = blockIdx.y, kt = blockIdx.x, qs = blockIdx.z;
  const int t = threadIdx.x, w = t>>6, l = t&63;
  const int half = (l>>4)&1, part = l>>5, lc = l&15;
  __shared__ __align__(16) unsigned short qhs[2048];
  __shared__ __align__(16) unsigned short qls[2048];
  __shared__ float ms[128];
  s16x8 ak[4];
  {
    const unsigned short* Ksrc = part ? Kl : Kh;
#pragma unroll
    for (int m=0;m<4;++m){
      const int key = kt*256 + w*64 + m*16 + lc;
      ak[m] = *(const s16x8*)(Ksrc + (((long)bh*L + key)*HD) + half*8);
    }
  }
  f32x4 csum[4];
#pragma unroll
  for (int m=0;m<4;++m){ csum[m][0]=csum[m][1]=csum[m][2]=csum[m][3]=0.f; }
  const s16x8* qhg = (const s16x8*)(Qh + (long)bh*L*HD);
  const s16x8* qlg = (const s16x8*)(Ql + (long)bh*L*HD);
  const int c0 = qs*KCH;
  s16x8 pk = qhg[c0*256 + t], pl = qlg[c0*256 + t];
  float pm = -3.4e38f;
  if (t < 128){
    const long qi = (long)c0*128 + t;
#pragma unroll
    for (int pp=0;pp<NSPLIT;++pp) pm = fmaxf(pm, mpart[((long)(pp*NBH+bh))*L + qi]);
    pm *= 1.44269504f;
  }
  for (int qc=0; qc<KCH; ++qc){
    __syncthreads();
    ((s16x8*)qhs)[t] = pk;
    ((s16x8*)qls)[t] = pl;
    if (t < 128) ms[t] = pm;
    if (qc+1 < KCH){
      pk = qhg[(c0+qc+1)*256 + t]; pl = qlg[(c0+qc+1)*256 + t];
      if (t < 128){
        const long qi = (long)(c0+qc+1)*128 + t;
        float nm = -3.4e38f;
#pragma unroll
        for (int pp=0;pp<NSPLIT;++pp) nm = fmaxf(nm, mpart[((long)(pp*NBH+bh))*L + qi]);
        pm = nm * 1.44269504f;
      }
    }
    __syncthreads();
#pragma unroll
    for (int s=0;s<8;++s){
      const int qq = s*16 + lc;
      s16x8 b1 = ((const s16x8*)qhs)[qq*2 + half];
      s16x8 b2 = ((const s16x8*)qls)[qq*2 + half];
      const float m2 = ms[qq];
#pragma unroll
      for (int m=0;m<4;++m){
        f32x4 acc = {0.f,0.f,0.f,0.f};
        acc = __builtin_amdgcn_mfma_f32_16x16x32_bf16(ak[m], b2, acc, 0,0,0);
        acc = __builtin_amdgcn_mfma_f32_16x16x32_bf16(ak[m], b1, acc, 0,0,0);
#pragma unroll
        for (int r=0;r<4;++r)
          csum[m][r] += fast_exp2(fmaf(acc[r], 0.36067376022224085f, -m2));
      }
    }
  }
#pragma unroll
  for (int m=0;m<4;++m){
#pragma unroll
    for (int r=0;r<4;++r){
      float v = csum[m][r];
      v += __shfl_xor(v, 1);
      v += __shfl_xor(v, 2);
      v += __shfl_xor(v, 4);
      v += __shfl_xor(v, 8);
      csum[m][r] = v;
    }
  }
  if (lc == 0){
    const int k4 = l>>4;
#pragma unroll
    for (int m=0;m<4;++m){
#pragma unroll
      for (int r=0;r<4;++r){
        const int key = kt*256 + w*64 + m*16 + k4*4 + r;
        cspart[((long)(qs*NBH + bh))*L + key] = csum[m][r];
      }
    }
  }
}

// ---------------- K4: radix-select top-41 + gather Ks/Vs ----------------
__global__ __launch_bounds__(256) void topk_gather(
    const float* __restrict__ cspart,
    const unsigned short* __restrict__ Kh, const unsigned short* __restrict__ Kl,
    const float* __restrict__ V,
    float* __restrict__ Ks, float* __restrict__ Vs)
{
  const int bh = blockIdx.x;
  const int t = threadIdx.x;
  __shared__ float vals[4096];
  __shared__ unsigned hist[2048];
  __shared__ unsigned suf[256];
  __shared__ int meta[4];
  __shared__ int sel[SK];
  __shared__ int sorted[SK];
  __shared__ int candi[4096];
  __shared__ float candv[4096];
  __shared__ float wbv[4]; __shared__ int wbi[4]; __shared__ int wbp[4];

  for (int i=t;i<2048;i+=256) hist[i]=0u;
  if (t==0){ meta[2]=0; meta[3]=0; }
  __syncthreads();
  for (int i=t;i<4096;i+=256){
    float s=0.f;
#pragma unroll
    for (int p=0;p<NSPLIT;++p) s += cspart[((long)(p*NBH+bh))*L + i];
    vals[i]=s;
    atomicAdd(&hist[__float_as_uint(s)>>21], 1u);
  }
  __syncthreads();
  {
    unsigned c=0;
#pragma unroll
    for (int b=0;b<8;++b) c += hist[t*8+b];
    suf[t]=c;
  }
  __syncthreads();
  for (int off=1; off<256; off<<=1){
    unsigned add = (t+off<256)? suf[t+off] : 0u;
    __syncthreads();
    suf[t] += add;
    __syncthreads();
  }
  {
    unsigned mysuf = suf[t];
    unsigned nxt = (t==255)?0u:suf[t+1];
    if (mysuf >= SK && nxt < SK){
      unsigned running = nxt;
      for (int b=t*8+7; b>=t*8; --b){
        unsigned h=hist[b];
        if (running + h >= SK){ meta[0]=b; meta[1]=(int)running; break; }
        running += h;
      }
    }
  }
  __syncthreads();
  const int B = meta[0];
  for (int i=t;i<4096;i+=256){
    int b = (int)(__float_as_uint(vals[i])>>21);
    if (b > B){
      int p = atomicAdd(&meta[2],1);
      sel[p]=i;
    } else if (b == B){
      int p = atomicAdd(&meta[3],1);
      candi[p]=i; candv[p]=vals[i];
    }
  }
  __syncthreads();
  const int nsel = meta[2];
  const int nc   = meta[3];
  const int r    = SK - nsel;
  for (int it=0; it<r; ++it){
    float bv=-1.f; int bi=0x7fffffff, bp=-1;
    for (int j=t;j<nc;j+=256){
      float v=candv[j];
      if (v>bv || (v==bv && candi[j]<bi)){ bv=v; bi=candi[j]; bp=j; }
    }
#pragma unroll
    for (int off=1;off<64;off<<=1){
      float ov=__shfl_xor(bv,off); int oi=__shfl_xor(bi,off); int op=__shfl_xor(bp,off);
      if (ov>bv || (ov==bv && oi<bi)){ bv=ov; bi=oi; bp=op; }
    }
    if ((t&63)==0){ int w=t>>6; wbv[w]=bv; wbi[w]=bi; wbp[w]=bp; }
    __syncthreads();
    if (t==0){
      float fv=wbv[0]; int fi=wbi[0], fp=wbp[0];
      for (int w=1;w<4;++w){
        if (wbv[w]>fv || (wbv[w]==fv && wbi[w]<fi)){ fv=wbv[w]; fi=wbi[w]; fp=wbp[w]; }
      }
      sel[nsel+it]=fi; candv[fp]=-1.f;
    }
    __syncthreads();
  }
  if (t<SK){
    int x=sel[t]; int rk=0;
    for (int j=0;j<SK;++j) rk += (sel[j]<x);
    sorted[rk]=x;
  }
  __syncthreads();
  for (int i=t;i<SK*HD;i+=256){
    const int j=i>>4, dd=i&15;
    const int key=sorted[j];
    const long src=((long)bh*L+key)*HD+dd;
    Ks[(long)bh*SK*HD+i]=bf2f(Kh[src])+bf2f(Kl[src]);
    Vs[(long)bh*SK*HD+i]=V[src];
  }
}

// ---------------- K5: sampled attention (online softmax over 41 keys) ----------------
__global__ __launch_bounds__(256) void sattn(
    const unsigned short* __restrict__ Qh, const unsigned short* __restrict__ Ql,
    const float* __restrict__ Ks, const float* __restrict__ Vs,
    unsigned short* __restrict__ AOh, unsigned short* __restrict__ AOl)
{
  const int bh = blockIdx.y, qb = blockIdx.x;
  const int t = threadIdx.x;
  __shared__ float ks[SK*HD], vs[SK*HD];
  for (int i=t; i<SK*HD; i+=256){
    ks[i] = Ks[(long)bh*SK*HD + i];
    vs[i] = Vs[(long)bh*SK*HD + i];
  }
  __syncthreads();
  const int q = qb*256 + t;
  const long qo = ((long)bh*L + q)*HD;
  float qv[16];
  {
    s16x8 h0 = *(const s16x8*)(Qh+qo);
    s16x8 h1 = *(const s16x8*)(Qh+qo+8);
    s16x8 l0 = *(const s16x8*)(Ql+qo);
    s16x8 l1 = *(const s16x8*)(Ql+qo+8);
#pragma unroll
    for (int d=0; d<8; ++d){
      qv[d]   = bf2f((unsigned short)h0[d]) + bf2f((unsigned short)l0[d]);
      qv[d+8] = bf2f((unsigned short)h1[d]) + bf2f((unsigned short)l1[d]);
    }
  }
  float mrun = -3.4e38f, lrun = 0.f, out[16];
#pragma unroll
  for (int d=0; d<16; ++d) out[d] = 0.f;
  for (int j=0; j<SK; ++j){
    float s = 0.f;
#pragma unroll
    for (int d=0; d<16; ++d) s = fmaf(qv[d], ks[j*HD+d], s);
    s *= 0.25f;
    if (s > mrun){
      const float c = __expf(mrun - s);
      lrun *= c;
#pragma unroll
      for (int d=0; d<16; ++d) out[d] *= c;
      mrun = s;
    }
    const float p = __expf(s - mrun);
    lrun += p;
#pragma unroll
    for (int d=0; d<16; ++d) out[d] = fmaf(p, vs[j*HD+d], out[d]);
  }
  const float inv = 1.f / lrun;
  const int b = bh>>3, h = bh&7;
  const long row = (long)b*L + q;
  unsigned short hv[16], lv[16];
#pragma unroll
  for (int d=0; d<16; ++d){
    const float v = out[d]*inv;
    hv[d] = f2bf(v);
    lv[d] = f2bf(v - bf2f(hv[d]));
  }
  unsigned short* oh = AOh + row*DM + h*HD;
  unsigned short* ol = AOl + row*DM + h*HD;
  *(uint4*)(oh)   = *(uint4*)(hv);
  *(uint4*)(oh+8) = *(uint4*)(hv+8);
  *(uint4*)(ol)   = *(uint4*)(lv);
  *(uint4*)(ol+8) = *(uint4*)(lv+8);
}

// ---------------- K6: MFMA output projection ----------------
__global__ __launch_bounds__(256) void outproj_mfma(
    const unsigned short* __restrict__ AOh, const unsigned short* __restrict__ AOl,
    const unsigned short* __restrict__ Wph, const unsigned short* __restrict__ Wpl,
    const float* __restrict__ bo, float* __restrict__ out)
{
  __shared__ __align__(16) unsigned short wh[16384];
  __shared__ __align__(16) unsigned short wl[16384];
  const int t = threadIdx.x;
  {
    const uint4* gh = (const uint4*)(Wph + (long)3*16384);
    const uint4* gl = (const uint4*)(Wpl + (long)3*16384);
    uint4* sh = (uint4*)wh; uint4* sl = (uint4*)wl;
#pragma unroll
    for (int i=0;i<8;++i){ sh[t + i*256] = gh[t + i*256]; sl[t + i*256] = gl[t + i*256]; }
  }
  __syncthreads();
  const int w = t>>6, l = t&63;
  const int lc = l&15, g = l>>4;
  const int mbase = blockIdx.x*256 + w*64;
  f32x4 acc[4][8];
#pragma unroll
  for (int mt=0;mt<4;++mt)
#pragma unroll
    for (int nt=0;nt<8;++nt){ acc[mt][nt][0]=0.f; acc[mt][nt][1]=0.f; acc[mt][nt][2]=0.f; acc[mt][nt][3]=0.f; }
  const unsigned short* __restrict__ Asrc = (g<2)? AOh : AOl;
  const int koff = (g&1)*8;
  for (int kc=0; kc<8; ++kc){
    s16x8 a[4];
#pragma unroll
    for (int mt=0;mt<4;++mt)
      a[mt] = *(const s16x8*)(Asrc + ((long)(mbase + mt*16 + lc))*128 + kc*16 + koff);
#pragma unroll
    for (int nt=0;nt<8;++nt){
      const int fi = (kc*2+(g&1))*128 + nt*16 + lc;
      s16x8 b1 = ((const s16x8*)wh)[fi];
      s16x8 b2 = ((const s16x8*)wl)[fi];
#pragma unroll
      for (int mt=0;mt<4;++mt){
        acc[mt][nt] = __builtin_amdgcn_mfma_f32_16x16x32_bf16(a[mt], b1, acc[mt][nt], 0,0,0);
        acc[mt][nt] = __builtin_amdgcn_mfma_f32_16x16x32_bf16(a[mt], b2, acc[mt][nt], 0,0,0);
      }
    }
  }
#pragma unroll
  for (int nt=0;nt<8;++nt){
    const float bb = bo[nt*16 + lc];
#pragma unroll
    for (int mt=0;mt<4;++mt){
#pragma unroll
      for (int r=0;r<4;++r){
        const int row = mbase + mt*16 + g*4 + r;
        out[(long)row*DM + nt*16 + lc] = acc[mt][nt][r] + bb;
      }
    }
  }
}

extern "C" void kernel_launch(void* const* d_in, const int* in_sizes, int n_in,
                              void* d_out, int out_size, void* d_ws, size_t ws_size,
                              hipStream_t stream)
{
  const float* x  = (const float*)d_in[0];
  const float* Wq = (const float*)d_in[1];
  const float* bq = (const float*)d_in[2];
  const float* Wk = (const float*)d_in[3];
  const float* bk = (const float*)d_in[4];
  const float* Wv = (const float*)d_in[5];
  const float* bv = (const float*)d_in[6];
  const float* Wo = (const float*)d_in[7];
  const float* bo = (const float*)d_in[8];
  float* out = (float*)d_out;

  char* wsp = (char*)d_ws;
  size_t o = 0;
  auto alloc = [&](size_t bytes)->char*{
    char* p = wsp + o; o += (bytes + 255) & ~(size_t)255; return p;
  };
  unsigned short* Qh = (unsigned short*)alloc((size_t)NBH*L*HD*2);
  unsigned short* Ql = (unsigned short*)alloc((size_t)NBH*L*HD*2);
  unsigned short* Kh = (unsigned short*)alloc((size_t)NBH*L*HD*2);
  unsigned short* Kl = (unsigned short*)alloc((size_t)NBH*L*HD*2);
  float* Vv    = (float*)alloc((size_t)NBH*L*HD*4);
  float* mpart = (float*)alloc((size_t)NSPLIT*NBH*L*4);
  float* cspart= (float*)alloc((size_t)NSPLIT*NBH*L*4);
  float* Ks    = (float*)alloc((size_t)NBH*SK*HD*4);
  float* Vs    = (float*)alloc((size_t)NBH*SK*HD*4);
  unsigned short* Xh  = (unsigned short*)alloc((size_t)2*L*DM*2);
  unsigned short* Xl  = (unsigned short*)alloc((size_t)2*L*DM*2);
  unsigned short* AOh = (unsigned short*)alloc((size_t)2*L*DM*2);
  unsigned short* AOl = (unsigned short*)alloc((size_t)2*L*DM*2);
  unsigned short* Wph = (unsigned short*)alloc((size_t)4*16384*2);
  unsigned short* Wpl = (unsigned short*)alloc((size_t)4*16384*2);

  prep<<<1280,256,0,stream>>>(x,Wq,Wk,Wv,Wo,Xh,Xl,Wph,Wpl);
  proj_mfma<<<dim3(32,3),256,0,stream>>>(Xh,Xl,Wph,Wpl,bq,bk,bv,Qh,Ql,Kh,Kl,Vv);
  rowmax_k<<<dim3(16,16,NSPLIT),256,0,stream>>>(Qh,Ql,Kh,Kl,mpart);
  colexp_k<<<dim3(16,16,NSPLIT),256,0,stream>>>(Kh,Kl,Qh,Ql,mpart,cspart);
  topk_gather<<<16,256,0,stream>>>(cspart,Kh,Kl,Vv,Ks,Vs);
  sattn<<<dim3(16,16),256,0,stream>>>(Qh,Ql,Ks,Vs,AOh,AOl);
  outproj_mfma<<<32,256,0,stream>>>(AOh,AOl,Wph,Wpl,bo,out);
}